// Round 6
// baseline (342.950 us; speedup 1.0000x reference)
//
#include <hip/hip_runtime.h>

#define BB 64
#define TT 4096
#define KK 48
#define UST 56              // stage1 Ubuf col stride (bf16): 112 B
#define UST2 72             // stage2 Ubuf col stride (bf16)
#define WS_LS_OFF 256
#define WS_U_OFF 32768
#define SEGBYTES 6144       // 48 rows x 64 col-stride x bf16

typedef __bf16 bf16_t;
typedef bf16_t bf16x8 __attribute__((ext_vector_type(8)));
typedef float f32x4 __attribute__((ext_vector_type(4)));
typedef float f32x16 __attribute__((ext_vector_type(16)));

__device__ __forceinline__ float fexp(float x) {   // natural exp
    return __builtin_amdgcn_exp2f(x * 1.4426950408889634f);
}
__device__ __forceinline__ float flog2(float x) { return __builtin_amdgcn_logf(x); }
__device__ __forceinline__ float rdlanef(float v, int l) {
    return __int_as_float(__builtin_amdgcn_readlane(__float_as_int(v), l));
}
__device__ __forceinline__ unsigned int bf16bits(float f) {
    return (unsigned int)__builtin_bit_cast(unsigned short, (bf16_t)f);
}
__device__ __forceinline__ float bf2f(bf16_t h) {
    return __uint_as_float(((unsigned int)__builtin_bit_cast(unsigned short, h)) << 16);
}

union SMem {
    struct {                                   // scores role (~15.4 KB)
        float sd[3328];
        float msk[257];
        int lab[257];
    } sc;
    struct {                                   // stage1 role (~18.8 KB)
        float4 exb[64 * 13];                   // [tt*13 + granule], fp32 ex
        bf16_t Ubuf[48 * UST + 16];
        unsigned long long pb;
        int lsb[4];
    } s1;
};

// ---------------- fused: scores-role blocks (first 1024) + stage1-role blocks ----------------
__global__ __launch_bounds__(256) void fused_kernel(
    const float* __restrict__ y_true, const float* __restrict__ y_pred,
    const float* __restrict__ trans, float* __restrict__ ws_target,
    int* __restrict__ ws_ls, bf16_t* __restrict__ ws_u, int nseg) {
    __shared__ SMem sm;
    const int tid = threadIdx.x;

    if (blockIdx.x < TT / 256 * BB) {
        // ================= scores role =================
        const int b = blockIdx.x >> 4;
        const int t0 = (blockIdx.x & 15) * 256;

        const float4* yt4 = (const float4*)(y_true + ((size_t)b * TT + t0) * KK);
        const float4* yp4 = (const float4*)(y_pred + ((size_t)b * TT + t0) * KK);

        float dv[12], lv[12], pv[12];
#pragma unroll
        for (int kk = 0; kk < 12; kk++) {
            int f = tid + 256 * kk;
            float4 a = yt4[f];
            float4 p = yp4[f];
            dv[kk] = fmaf(a.x, p.x, fmaf(a.y, p.y, fmaf(a.z, p.z, a.w * p.w)));
            float e0 = (float)(4 * (f % 12));
            lv[kk] = fmaf(a.x, e0, fmaf(a.y, e0 + 1.0f, fmaf(a.z, e0 + 2.0f, a.w * (e0 + 3.0f))));
            pv[kk] = fminf(fminf(p.x, p.y), fminf(p.z, p.w));
        }

        if (tid == 0) {
            if (t0 + 256 < TT) {
                const float4* at = (const float4*)(y_true + ((size_t)b * TT + t0 + 256) * KK);
                const float4* pt = (const float4*)(y_pred + ((size_t)b * TT + t0 + 256) * KK);
                float lb = 0.0f, pm = 1e30f;
#pragma unroll
                for (int g = 0; g < 12; g++) {
                    float4 a = at[g]; float4 p = pt[g];
                    float e0 = (float)(4 * g);
                    lb = fmaf(a.x, e0, fmaf(a.y, e0 + 1.0f, fmaf(a.z, e0 + 2.0f, fmaf(a.w, e0 + 3.0f, lb))));
                    pm = fminf(pm, fminf(fminf(p.x, p.y), fminf(p.z, p.w)));
                }
                sm.sc.lab[256] = (int)(lb + 0.5f);
                sm.sc.msk[256] = (pm > -1e6f) ? 1.0f : 0.0f;
            } else {
                sm.sc.lab[256] = 0; sm.sc.msk[256] = 0.0f;
            }
        }

        float dval = 0.0f, lval = 0.0f, pval = 1e30f;
        // pass 1: dot
#pragma unroll
        for (int kk = 0; kk < 12; kk++) { int f = tid + 256 * kk; sm.sc.sd[f + f / 12] = dv[kk]; }
        __syncthreads();
#pragma unroll
        for (int j = 0; j < 12; j++) dval += sm.sc.sd[13 * tid + j];
        __syncthreads();
        // pass 2: label
#pragma unroll
        for (int kk = 0; kk < 12; kk++) { int f = tid + 256 * kk; sm.sc.sd[f + f / 12] = lv[kk]; }
        __syncthreads();
#pragma unroll
        for (int j = 0; j < 12; j++) lval += sm.sc.sd[13 * tid + j];
        __syncthreads();
        // pass 3: pmin
#pragma unroll
        for (int kk = 0; kk < 12; kk++) { int f = tid + 256 * kk; sm.sc.sd[f + f / 12] = pv[kk]; }
        __syncthreads();
#pragma unroll
        for (int j = 0; j < 12; j++) pval = fminf(pval, sm.sc.sd[13 * tid + j]);

        sm.sc.msk[tid] = (pval > -1e6f) ? 1.0f : 0.0f;
        sm.sc.lab[tid] = (int)(lval + 0.5f);
        __syncthreads();

        const float m = sm.sc.msk[tid];
        float contrib = m * dval;
        int t = t0 + tid;
        if (t < TT - 1) {
            contrib += m * sm.sc.msk[tid + 1] * trans[sm.sc.lab[tid] * KK + sm.sc.lab[tid + 1]];
        }
#pragma unroll
        for (int off = 32; off; off >>= 1) contrib += __shfl_xor(contrib, off);
        if ((tid & 63) == 0) atomicAdd(&ws_target[b], contrib);
        return;
    }

    // ================= stage1 role =================
    const int id = blockIdx.x - TT / 256 * BB;
    const int s = id % nseg, b = id / nseg;
    const int seglen = TT / nseg;
    const int nch = seglen / 64;
    const int w = tid >> 6;         // waves 0..2 compute, wave 3 produces
    const int lane = tid & 63;
    const int q = lane >> 4;
    const int n = lane & 15;
    const int ncol = 16 * w + n;

    // A fragments: E^T zero-padded in K. A[m][k]: m = 16*mt + n, k = 32*ks + 8*q + j.
    bf16x8 afrag[3][2];
    if (w < 3) {
#pragma unroll
        for (int mt = 0; mt < 3; mt++) {
#pragma unroll
            for (int ks = 0; ks < 2; ks++) {
                bf16x8 f;
#pragma unroll
                for (int j = 0; j < 8; j++) {
                    int m = 16 * mt + n;
                    int k = 32 * ks + 8 * q + j;
                    float v = (k < KK) ? fexp(trans[k * KK + m]) : 0.0f;
                    f[j] = (bf16_t)v;
                }
                afrag[mt][ks] = f;
            }
        }
    }

    // zero Ubuf
    {
        uint4* p = (uint4*)sm.s1.Ubuf;
        for (int i = tid; i < (48 * UST + 16) / 8; i += 256) p[i] = make_uint4(0, 0, 0, 0);
    }
    __syncthreads();
    if (tid < KK) sm.s1.Ubuf[tid * UST + tid] = (bf16_t)1.0f;

    const bf16_t* bptr0 = &sm.s1.Ubuf[ncol * UST + 8 * q];
    const bf16_t* bptr1 = &sm.s1.Ubuf[ncol * UST + 32 + 8 * q];
    bf16_t* wp0 = &sm.s1.Ubuf[ncol * UST + 0 + 4 * q];
    bf16_t* wp1 = &sm.s1.Ubuf[ncol * UST + 16 + 4 * q];
    bf16_t* wp2 = &sm.s1.Ubuf[ncol * UST + 32 + 4 * q];

    f32x4 z4 = {0.0f, 0.0f, 0.0f, 0.0f};
    int ls = 0;

    for (int ch = 0; ch < nch; ch++) {
        __syncthreads();   // computes done with previous exb
        if (w == 3) {
            // producer: stage 64 timesteps of fp32 ex + ballot; lane = local t
            const float* xr = y_pred + ((size_t)b * TT + s * seglen + ch * 64 + lane) * KK;
            float pm = 1e30f;
#pragma unroll
            for (int g = 0; g < 12; g++) {
                float4 v = *(const float4*)(xr + 4 * g);
                pm = fminf(pm, fminf(fminf(v.x, v.y), fminf(v.z, v.w)));
                sm.s1.exb[lane * 13 + g] = make_float4(fexp(v.x), fexp(v.y), fexp(v.z), fexp(v.w));
            }
            unsigned long long bal = __ballot(pm > -1e6f);
            if (lane == 0) sm.s1.pb = bal;
        }
        __syncthreads();
        if (w < 3) {
            const unsigned long long mk = sm.s1.pb;
            const int tt0 = (s == 0 && ch == 0) ? 1 : 0;
            for (int tt = tt0; tt < 64; tt++) {
                if (!((mk >> tt) & 1ull)) continue;

                bf16x8 bf0 = __builtin_bit_cast(bf16x8, *(const uint4*)bptr0);
                bf16x8 bf1 = __builtin_bit_cast(bf16x8, *(const uint4*)bptr1);

                f32x4 acc0 = __builtin_amdgcn_mfma_f32_16x16x32_bf16(afrag[0][0], bf0, z4, 0, 0, 0);
                acc0 = __builtin_amdgcn_mfma_f32_16x16x32_bf16(afrag[0][1], bf1, acc0, 0, 0, 0);
                f32x4 acc1 = __builtin_amdgcn_mfma_f32_16x16x32_bf16(afrag[1][0], bf0, z4, 0, 0, 0);
                acc1 = __builtin_amdgcn_mfma_f32_16x16x32_bf16(afrag[1][1], bf1, acc1, 0, 0, 0);
                f32x4 acc2 = __builtin_amdgcn_mfma_f32_16x16x32_bf16(afrag[2][0], bf0, z4, 0, 0, 0);
                acc2 = __builtin_amdgcn_mfma_f32_16x16x32_bf16(afrag[2][1], bf1, acc2, 0, 0, 0);

                float4 ex0 = sm.s1.exb[tt * 13 + q];        // rows 4q..4q+3
                float4 ex1 = sm.s1.exb[tt * 13 + 4 + q];    // rows 16+4q..
                float4 ex2 = sm.s1.exb[tt * 13 + 8 + q];    // rows 32+4q..

                float v00 = rdlanef(acc0[0], 0);
                float e00 = rdlanef(ex0.x, 0);
                float sc = v00 * e00;                       // > 0
                int k = (int)(__float_as_uint(sc) >> 23) - 127;
                float r = __uint_as_float((unsigned int)(127 - k) << 23);   // 2^-k exact
                ls += k;

                {
                    float o0 = acc0[0] * (ex0.x * r), o1 = acc0[1] * (ex0.y * r);
                    float o2 = acc0[2] * (ex0.z * r), o3 = acc0[3] * (ex0.w * r);
                    *(uint2*)wp0 = make_uint2(bf16bits(o0) | (bf16bits(o1) << 16),
                                              bf16bits(o2) | (bf16bits(o3) << 16));
                }
                {
                    float o0 = acc1[0] * (ex1.x * r), o1 = acc1[1] * (ex1.y * r);
                    float o2 = acc1[2] * (ex1.z * r), o3 = acc1[3] * (ex1.w * r);
                    *(uint2*)wp1 = make_uint2(bf16bits(o0) | (bf16bits(o1) << 16),
                                              bf16bits(o2) | (bf16bits(o3) << 16));
                }
                {
                    float o0 = acc2[0] * (ex2.x * r), o1 = acc2[1] * (ex2.y * r);
                    float o2 = acc2[2] * (ex2.z * r), o3 = acc2[3] * (ex2.w * r);
                    *(uint2*)wp2 = make_uint2(bf16bits(o0) | (bf16bits(o1) << 16),
                                              bf16bits(o2) | (bf16bits(o3) << 16));
                }
            }
        }
    }

    // reconcile per-wave pow2 scales (exact), write compact 48x64 bf16 block
    if (w < 3 && lane == 0) sm.s1.lsb[w] = ls;
    __syncthreads();
    if (w < 3 && lane < KK) {
        const int dl = ls - sm.s1.lsb[0];
        bf16_t* Uo = ws_u + (size_t)(b * nseg + s) * 3072;
        unsigned int wd[8];
#pragma unroll
        for (int j = 0; j < 8; j++) {
            float f0 = ldexpf(bf2f(sm.s1.Ubuf[(16 * w + 2 * j) * UST + lane]), dl);
            float f1 = ldexpf(bf2f(sm.s1.Ubuf[(16 * w + 2 * j + 1) * UST + lane]), dl);
            wd[j] = bf16bits(f0) | (bf16bits(f1) << 16);
        }
        *(uint4*)(Uo + (size_t)lane * 64 + 16 * w) = make_uint4(wd[0], wd[1], wd[2], wd[3]);
        *(uint4*)(Uo + (size_t)lane * 64 + 16 * w + 8) = make_uint4(wd[4], wd[5], wd[6], wd[7]);
    }
    if (tid == 0) ws_ls[b * nseg + s] = sm.s1.lsb[0];
}

// ---------------- stage 2: chain nseg segment matrices, apply q0, logsumexp ----------------
__global__ __launch_bounds__(64) void stage2_kernel(
    const float* __restrict__ y_pred, const bf16_t* __restrict__ ws_u,
    const int* __restrict__ ws_ls, const float* __restrict__ ws_target,
    float* __restrict__ out, int nseg) {
    const int b = blockIdx.x;
    const int lane = threadIdx.x;
    const int half = lane >> 5;
    const int l31 = lane & 31;

    __shared__ __align__(16) bf16_t Ub[64 * UST2];

    for (int i = lane; i < 64 * UST2 / 8; i += 64) ((uint4*)Ub)[i] = make_uint4(0, 0, 0, 0);
    if (lane < KK) Ub[lane * UST2 + lane] = (bf16_t)1.0f;   // same-wave ds ordering

    f32x16 z16;
#pragma unroll
    for (int r = 0; r < 16; r++) z16[r] = 0.0f;

    int ls2 = 0;
    for (int s2 = 0; s2 < nseg; s2++) {   // W <- U_s * W
        const bf16_t* Us = ws_u + (size_t)(b * nseg + s2) * 3072;
        bf16x8 af[2][3];
#pragma unroll
        for (int mt = 0; mt < 2; mt++) {
            int m = l31 + 32 * mt;
#pragma unroll
            for (int ks = 0; ks < 3; ks++) {
                if (m < KK) {
                    af[mt][ks] = __builtin_bit_cast(bf16x8,
                        *(const uint4*)&Us[(size_t)m * 64 + 16 * ks + 8 * half]);
                } else {
                    af[mt][ks] = __builtin_bit_cast(bf16x8, make_uint4(0, 0, 0, 0));
                }
            }
        }
        bf16x8 bg[3][2];
#pragma unroll
        for (int ks = 0; ks < 3; ks++)
#pragma unroll
            for (int nt = 0; nt < 2; nt++)
                bg[ks][nt] = __builtin_bit_cast(bf16x8,
                    *(const uint4*)&Ub[(l31 + 32 * nt) * UST2 + 16 * ks + 8 * half]);

        f32x16 acc[4];
#pragma unroll
        for (int mt = 0; mt < 2; mt++)
#pragma unroll
            for (int nt = 0; nt < 2; nt++) {
                f32x16 a0 = __builtin_amdgcn_mfma_f32_32x32x16_bf16(af[mt][0], bg[0][nt], z16, 0, 0, 0);
                a0 = __builtin_amdgcn_mfma_f32_32x32x16_bf16(af[mt][1], bg[1][nt], a0, 0, 0, 0);
                acc[mt * 2 + nt] = __builtin_amdgcn_mfma_f32_32x32x16_bf16(af[mt][2], bg[2][nt], a0, 0, 0, 0);
            }

        float v00 = rdlanef(acc[0][0], 0);
        int k = (int)(__float_as_uint(v00) >> 23) - 127;
        float r = __uint_as_float((unsigned int)(127 - k) << 23);
        ls2 += k;

#pragma unroll
        for (int mt = 0; mt < 2; mt++)
#pragma unroll
            for (int nt = 0; nt < 2; nt++) {
                int c = l31 + 32 * nt;
#pragma unroll
                for (int g = 0; g < 4; g++) {
                    int a0 = 32 * mt + 8 * g + 4 * half;
                    const f32x16& A = acc[mt * 2 + nt];
                    unsigned int w0 = bf16bits(A[4 * g + 0] * r) | (bf16bits(A[4 * g + 1] * r) << 16);
                    unsigned int w1 = bf16bits(A[4 * g + 2] * r) | (bf16bits(A[4 * g + 3] * r) << 16);
                    *(uint2*)&Ub[c * UST2 + a0] = make_uint2(w0, w1);
                }
            }
    }

    int lsum = (lane < nseg) ? ws_ls[b * nseg + lane] : 0;
#pragma unroll
    for (int off = 32; off; off >>= 1) lsum += __shfl_xor(lsum, off);
    float L = (float)(lsum + ls2);

    // q0 from t=0 row
    float x0 = (lane < KK) ? y_pred[(size_t)b * TT * KK + lane] : 0.0f;
    bool ok0 = (lane >= KK) || (x0 > -1e6f);
    bool m0 = (__ballot(ok0) == ~0ull);
    float xeff = (lane < KK) ? (m0 ? x0 : 0.0f) : 0.0f;
    float c0 = rdlanef(xeff, 0);
    float q0 = (lane < KK) ? fexp(xeff - c0) : 0.0f;

    float p = 0.0f;
    for (int c = 0; c < KK; c++) {
        float qc = rdlanef(q0, c);
        p = fmaf(bf2f(Ub[c * UST2 + lane]), qc, p);
    }
#pragma unroll
    for (int off = 32; off; off >>= 1) p += __shfl_xor(p, off);

    if (lane == 0) {
        out[b] = c0 + 0.6931471805599453f * (L + flog2(p)) - ws_target[b];
    }
}

extern "C" void kernel_launch(void* const* d_in, const int* in_sizes, int n_in,
                              void* d_out, int out_size, void* d_ws, size_t ws_size,
                              hipStream_t stream) {
    const float* y_true = (const float*)d_in[0];
    const float* y_pred = (const float*)d_in[1];
    const float* trans = (const float*)d_in[2];
    float* out = (float*)d_out;

    // adaptive segment count based on workspace size (r3 lesson: never overrun d_ws)
    int nseg = 16;
    if (ws_size >= (size_t)WS_U_OFF + (size_t)BB * 64 * SEGBYTES) nseg = 64;
    else if (ws_size >= (size_t)WS_U_OFF + (size_t)BB * 32 * SEGBYTES) nseg = 32;

    float* ws_target = (float*)d_ws;
    int* ws_ls = (int*)((char*)d_ws + WS_LS_OFF);
    bf16_t* ws_u = (bf16_t*)((char*)d_ws + WS_U_OFF);

    hipMemsetAsync(ws_target, 0, BB * sizeof(float), stream);
    fused_kernel<<<TT / 256 * BB + nseg * BB, 256, 0, stream>>>(
        y_true, y_pred, trans, ws_target, ws_ls, ws_u, nseg);
    stage2_kernel<<<BB, 64, 0, stream>>>(y_pred, ws_u, ws_ls, ws_target, out, nseg);
}

// Round 7
// 311.470 us; speedup vs baseline: 1.1011x; 1.1011x over previous
//
#include <hip/hip_runtime.h>

#define BB 64
#define TT 4096
#define KK 48
#define UST 56              // stage1 Ubuf col stride (bf16): 112 B
#define PST 56              // phaseA/B LDS col stride (bf16): rows 0..47 (+guarded writes)
#define WS_LS_OFF 256
#define WS_U_OFF 32768
#define SEGBYTES 6144       // 48 rows x 64 col-stride x bf16

typedef __bf16 bf16_t;
typedef bf16_t bf16x8 __attribute__((ext_vector_type(8)));
typedef float f32x4 __attribute__((ext_vector_type(4)));
typedef float f32x16 __attribute__((ext_vector_type(16)));

__device__ __forceinline__ float fexp(float x) {   // natural exp
    return __builtin_amdgcn_exp2f(x * 1.4426950408889634f);
}
__device__ __forceinline__ float flog2(float x) { return __builtin_amdgcn_logf(x); }
__device__ __forceinline__ float rdlanef(float v, int l) {
    return __int_as_float(__builtin_amdgcn_readlane(__float_as_int(v), l));
}
__device__ __forceinline__ unsigned int bf16bits(float f) {
    return (unsigned int)__builtin_bit_cast(unsigned short, (bf16_t)f);
}
__device__ __forceinline__ float bf2f(bf16_t h) {
    return __uint_as_float(((unsigned int)__builtin_bit_cast(unsigned short, h)) << 16);
}
__device__ __forceinline__ float ubf_lo(unsigned int w) { return __uint_as_float(w << 16); }
__device__ __forceinline__ float ubf_hi(unsigned int w) { return __uint_as_float(w & 0xffff0000u); }

// ============ fused: stage1 (waves 0-2) + ex-staging & scores (wave 3) ============
__global__ __launch_bounds__(256, 6) void fused_kernel(
    const float* __restrict__ y_true, const float* __restrict__ y_pred,
    const float* __restrict__ trans, float* __restrict__ ws_target,
    int* __restrict__ ws_ls, bf16_t* __restrict__ ws_u, int nseg) {
    const int s = blockIdx.x, b = blockIdx.y;
    const int seglen = TT / nseg;
    const int nch = seglen / 64;
    const int tid = threadIdx.x;
    const int w = tid >> 6;
    const int lane = tid & 63;
    const int q = lane >> 4;
    const int n = lane & 15;
    const int ncol = 16 * w + n;

    __shared__ __align__(16) uint2 exb[64 * 13];              // bf16x4 ex granules
    __shared__ __align__(16) bf16_t Ubuf[48 * UST + 16];
    __shared__ unsigned long long pb;
    __shared__ int lsb[4];

    // A fragments (waves 0-2): E^T zero-padded in K. A[m][k]: m=16mt+n, k=32ks+8q+j.
    bf16x8 afrag[3][2];
    if (w < 3) {
#pragma unroll
        for (int mt = 0; mt < 3; mt++) {
#pragma unroll
            for (int ks = 0; ks < 2; ks++) {
                bf16x8 f;
#pragma unroll
                for (int j = 0; j < 8; j++) {
                    int k = 32 * ks + 8 * q + j;
                    float v = (k < KK) ? fexp(trans[k * KK + 16 * mt + n]) : 0.0f;
                    f[j] = (bf16_t)v;
                }
                afrag[mt][ks] = f;
            }
        }
    }

    {   // zero Ubuf then identity diag
        uint4* p = (uint4*)Ubuf;
        for (int i = tid; i < (48 * UST + 16) / 8; i += 256) p[i] = make_uint4(0, 0, 0, 0);
    }
    __syncthreads();
    if (tid < KK) Ubuf[tid * UST + tid] = (bf16_t)1.0f;

    const bf16_t* bptr0 = &Ubuf[ncol * UST + 8 * q];
    const bf16_t* bptr1 = &Ubuf[ncol * UST + 32 + 8 * q];
    bf16_t* wp0 = &Ubuf[ncol * UST + 0 + 4 * q];
    bf16_t* wp1 = &Ubuf[ncol * UST + 16 + 4 * q];
    bf16_t* wp2 = &Ubuf[ncol * UST + 32 + 4 * q];

    f32x4 z4 = {0.0f, 0.0f, 0.0f, 0.0f};
    int ls = 0;
    float sc_acc = 0.0f;   // wave3: scores accumulator

    for (int ch = 0; ch < nch; ch++) {
        __syncthreads();                     // previous exb fully consumed
        if (w == 3) {
            // ---- producer + scores: lane = local timestep ----
            const int t0c = s * seglen + ch * 64;
            const float4* yp4 = (const float4*)(y_pred + (size_t)(t0c + lane) * KK);
            const float4* yt4 = (const float4*)(y_true + (size_t)(t0c + lane) * KK);
            float dot = 0.0f, labf = 0.0f, pmin = 1e30f;
            uint2* exrow = &exb[lane * 13];
#pragma unroll 4
            for (int g = 0; g < 12; g++) {
                float4 p = yp4[g];
                float4 a = yt4[g];
                dot = fmaf(a.x, p.x, fmaf(a.y, p.y, fmaf(a.z, p.z, fmaf(a.w, p.w, dot))));
                float e0 = (float)(4 * g);
                labf = fmaf(a.x, e0, fmaf(a.y, e0 + 1.0f, fmaf(a.z, e0 + 2.0f, fmaf(a.w, e0 + 3.0f, labf))));
                pmin = fminf(pmin, fminf(fminf(p.x, p.y), fminf(p.z, p.w)));
                exrow[g] = make_uint2(bf16bits(fexp(p.x)) | (bf16bits(fexp(p.y)) << 16),
                                      bf16bits(fexp(p.z)) | (bf16bits(fexp(p.w)) << 16));
            }
            bool mt_ok = pmin > -1e6f;
            unsigned long long bal = __ballot(mt_ok);
            if (lane == 0) pb = bal;

            // boundary row t0c+64 (label+mask), lanes 0..11 partials
            float labB = 0.0f, pmB = 1e30f;
            const bool hasB = (t0c + 64 < TT);
            if (hasB && lane < 12) {
                float4 a = ((const float4*)(y_true + (size_t)(t0c + 64) * KK))[lane];
                float4 p = ((const float4*)(y_pred + (size_t)(t0c + 64) * KK))[lane];
                float e0 = (float)(4 * lane);
                labB = fmaf(a.x, e0, fmaf(a.y, e0 + 1.0f, fmaf(a.z, e0 + 2.0f, a.w * (e0 + 3.0f))));
                pmB = fminf(fminf(p.x, p.y), fminf(p.z, p.w));
            }
#pragma unroll
            for (int off = 1; off < 16; off <<= 1) {
                labB += __shfl_xor(labB, off);
                pmB = fminf(pmB, __shfl_xor(pmB, off));
            }
            int labB_i = (int)(rdlanef(labB, 0) + 0.5f);
            float mB = (hasB && rdlanef(pmB, 0) > -1e6f) ? 1.0f : 0.0f;

            int labt = (int)(labf + 0.5f);
            float mft = mt_ok ? 1.0f : 0.0f;
            int lnx = __shfl(labt, (lane + 1) & 63);
            float mnx = __shfl(mft, (lane + 1) & 63);
            if (lane == 63) { lnx = labB_i; mnx = mB; }
            sc_acc += mft * dot + mft * mnx * trans[labt * KK + lnx];
        }
        __syncthreads();
        if (w < 3) {
            const unsigned long long mk = pb;
            const int tt0 = (s == 0 && ch == 0) ? 1 : 0;
            for (int tt = tt0; tt < 64; tt++) {
                if (!((mk >> tt) & 1ull)) continue;

                bf16x8 bf0 = __builtin_bit_cast(bf16x8, *(const uint4*)bptr0);
                bf16x8 bf1 = __builtin_bit_cast(bf16x8, *(const uint4*)bptr1);

                f32x4 acc0 = __builtin_amdgcn_mfma_f32_16x16x32_bf16(afrag[0][0], bf0, z4, 0, 0, 0);
                acc0 = __builtin_amdgcn_mfma_f32_16x16x32_bf16(afrag[0][1], bf1, acc0, 0, 0, 0);
                f32x4 acc1 = __builtin_amdgcn_mfma_f32_16x16x32_bf16(afrag[1][0], bf0, z4, 0, 0, 0);
                acc1 = __builtin_amdgcn_mfma_f32_16x16x32_bf16(afrag[1][1], bf1, acc1, 0, 0, 0);
                f32x4 acc2 = __builtin_amdgcn_mfma_f32_16x16x32_bf16(afrag[2][0], bf0, z4, 0, 0, 0);
                acc2 = __builtin_amdgcn_mfma_f32_16x16x32_bf16(afrag[2][1], bf1, acc2, 0, 0, 0);

                uint2 w0 = exb[tt * 13 + q];          // ex rows 4q..4q+3
                uint2 w1 = exb[tt * 13 + 4 + q];      // ex rows 16+4q..
                uint2 w2 = exb[tt * 13 + 8 + q];      // ex rows 32+4q..
                float e00 = ubf_lo(w0.x), e01 = ubf_hi(w0.x), e02 = ubf_lo(w0.y), e03 = ubf_hi(w0.y);
                float e10 = ubf_lo(w1.x), e11 = ubf_hi(w1.x), e12 = ubf_lo(w1.y), e13 = ubf_hi(w1.y);
                float e20 = ubf_lo(w2.x), e21 = ubf_hi(w2.x), e22 = ubf_lo(w2.y), e23 = ubf_hi(w2.y);

                float v00 = rdlanef(acc0[0], 0);
                float sc = v00 * rdlanef(e00, 0);     // > 0
                int k = (int)(__float_as_uint(sc) >> 23) - 127;
                float r = __uint_as_float((unsigned int)(127 - k) << 23);   // 2^-k exact
                ls += k;

                {
                    float o0 = acc0[0] * (e00 * r), o1 = acc0[1] * (e01 * r);
                    float o2 = acc0[2] * (e02 * r), o3 = acc0[3] * (e03 * r);
                    *(uint2*)wp0 = make_uint2(bf16bits(o0) | (bf16bits(o1) << 16),
                                              bf16bits(o2) | (bf16bits(o3) << 16));
                }
                {
                    float o0 = acc1[0] * (e10 * r), o1 = acc1[1] * (e11 * r);
                    float o2 = acc1[2] * (e12 * r), o3 = acc1[3] * (e13 * r);
                    *(uint2*)wp1 = make_uint2(bf16bits(o0) | (bf16bits(o1) << 16),
                                              bf16bits(o2) | (bf16bits(o3) << 16));
                }
                {
                    float o0 = acc2[0] * (e20 * r), o1 = acc2[1] * (e21 * r);
                    float o2 = acc2[2] * (e22 * r), o3 = acc2[3] * (e23 * r);
                    *(uint2*)wp2 = make_uint2(bf16bits(o0) | (bf16bits(o1) << 16),
                                              bf16bits(o2) | (bf16bits(o3) << 16));
                }
            }
        }
    }

    // wave3: one atomic per block with the scores contribution
    if (w == 3) {
#pragma unroll
        for (int off = 32; off; off >>= 1) sc_acc += __shfl_xor(sc_acc, off);
        if (lane == 0) atomicAdd(&ws_target[b], sc_acc);
    }

    // reconcile per-wave pow2 scales (exact), write compact 48x64 bf16 block
    if (w < 3 && lane == 0) lsb[w] = ls;
    __syncthreads();
    if (w < 3 && lane < KK) {
        const int dl = ls - lsb[0];
        bf16_t* Uo = ws_u + (size_t)(b * nseg + s) * 3072;
        unsigned int wd[8];
#pragma unroll
        for (int j = 0; j < 8; j++) {
            float f0 = ldexpf(bf2f(Ubuf[(16 * w + 2 * j) * UST + lane]), dl);
            float f1 = ldexpf(bf2f(Ubuf[(16 * w + 2 * j + 1) * UST + lane]), dl);
            wd[j] = bf16bits(f0) | (bf16bits(f1) << 16);
        }
        *(uint4*)(Uo + (size_t)lane * 64 + 16 * w) = make_uint4(wd[0], wd[1], wd[2], wd[3]);
        *(uint4*)(Uo + (size_t)lane * 64 + 16 * w + 8) = make_uint4(wd[4], wd[5], wd[6], wd[7]);
    }
    if (tid == 0) ws_ls[b * nseg + s] = lsb[0];
}

// 48x48 product helper: D = A (global row-major, 48x64) x W (LDS col-major, [n][k] stride PST).
// Result written back into LDS col-major; returns pow2 scale exponent taken out.
__device__ __forceinline__ int chain_product(const bf16_t* __restrict__ A, bf16_t* Ub, int lane) {
    const int half = lane >> 5;
    const int l31 = lane & 31;
    f32x16 z16;
#pragma unroll
    for (int r = 0; r < 16; r++) z16[r] = 0.0f;

    bf16x8 af[2][3];
#pragma unroll
    for (int mt = 0; mt < 2; mt++) {
        int m = l31 + 32 * mt;
#pragma unroll
        for (int ks = 0; ks < 3; ks++) {
            if (m < KK)
                af[mt][ks] = __builtin_bit_cast(bf16x8, *(const uint4*)&A[(size_t)m * 64 + 16 * ks + 8 * half]);
            else
                af[mt][ks] = __builtin_bit_cast(bf16x8, make_uint4(0, 0, 0, 0));
        }
    }
    bf16x8 bg[3][2];
#pragma unroll
    for (int ks = 0; ks < 3; ks++)
#pragma unroll
        for (int nt = 0; nt < 2; nt++)
            bg[ks][nt] = __builtin_bit_cast(bf16x8, *(const uint4*)&Ub[(l31 + 32 * nt) * PST + 16 * ks + 8 * half]);

    f32x16 acc[4];
#pragma unroll
    for (int mt = 0; mt < 2; mt++)
#pragma unroll
        for (int nt = 0; nt < 2; nt++) {
            f32x16 a0 = __builtin_amdgcn_mfma_f32_32x32x16_bf16(af[mt][0], bg[0][nt], z16, 0, 0, 0);
            a0 = __builtin_amdgcn_mfma_f32_32x32x16_bf16(af[mt][1], bg[1][nt], a0, 0, 0, 0);
            acc[mt * 2 + nt] = __builtin_amdgcn_mfma_f32_32x32x16_bf16(af[mt][2], bg[2][nt], a0, 0, 0, 0);
        }

    float v00 = rdlanef(acc[0][0], 0);
    int k = (int)(__float_as_uint(v00) >> 23) - 127;
    float r = __uint_as_float((unsigned int)(127 - k) << 23);

#pragma unroll
    for (int mt = 0; mt < 2; mt++)
#pragma unroll
        for (int nt = 0; nt < 2; nt++) {
            int c = l31 + 32 * nt;
#pragma unroll
            for (int g = 0; g < 4; g++) {
                int a0 = 32 * mt + 8 * g + 4 * half;
                if (a0 < KK) {   // rows >= 48 are zero; never write (stride is 56)
                    const f32x16& Aq = acc[mt * 2 + nt];
                    unsigned int u0 = bf16bits(Aq[4 * g + 0] * r) | (bf16bits(Aq[4 * g + 1] * r) << 16);
                    unsigned int u1 = bf16bits(Aq[4 * g + 2] * r) | (bf16bits(Aq[4 * g + 3] * r) << 16);
                    *(uint2*)&Ub[c * PST + a0] = make_uint2(u0, u1);
                }
            }
        }
    return k;
}

// ============ phase A: fold GROUP consecutive segment matrices, in place ============
__global__ __launch_bounds__(64) void phaseA_kernel(
    const int group, bf16_t* __restrict__ ws_u, int* __restrict__ ws_ls, int nseg) {
    const int g = blockIdx.x, b = blockIdx.y;
    const int lane = threadIdx.x;
    __shared__ __align__(16) bf16_t Ub[64 * PST];

    bf16_t* slot0 = ws_u + (size_t)(b * nseg + group * g) * 3072;
    // load first matrix into LDS col-major (cols >= 48 zero)
    for (int k = 0; k < KK; k++)
        Ub[lane * PST + k] = (lane < KK) ? slot0[(size_t)k * 64 + lane] : (bf16_t)0.0f;

    int lsk = ws_ls[b * nseg + group * g];
    __syncthreads();

    for (int j = 1; j < group; j++) {
        const bf16_t* A = ws_u + (size_t)(b * nseg + group * g + j) * 3072;
        lsk += ws_ls[b * nseg + group * g + j];
        lsk += chain_product(A, Ub, lane);
        __syncthreads();
    }

    // store back row-major into slot0 (cols >= 48 now zero)
    for (int k = 0; k < KK; k++)
        slot0[(size_t)k * 64 + lane] = Ub[lane * PST + k];
    if (lane == 0) ws_ls[b * nseg + group * g] = lsk;
}

// ============ phase B: chain the 16 supersegments, apply q0, logsumexp ============
__global__ __launch_bounds__(64) void phaseB_kernel(
    const float* __restrict__ y_pred, const bf16_t* __restrict__ ws_u,
    const int* __restrict__ ws_ls, const float* __restrict__ ws_target,
    float* __restrict__ out, int group, int nseg) {
    const int b = blockIdx.x;
    const int lane = threadIdx.x;
    __shared__ __align__(16) bf16_t Ub[64 * PST];

    const bf16_t* slot0 = ws_u + (size_t)(b * nseg) * 3072;
    for (int k = 0; k < KK; k++)
        Ub[lane * PST + k] = (lane < KK) ? slot0[(size_t)k * 64 + lane] : (bf16_t)0.0f;
    __syncthreads();

    int ls2 = 0;
    for (int g = 1; g < 16; g++) {
        const bf16_t* A = ws_u + (size_t)(b * nseg + group * g) * 3072;
        ls2 += chain_product(A, Ub, lane);
        __syncthreads();
    }

    int lsv = (lane < 16) ? ws_ls[b * nseg + group * lane] : 0;
#pragma unroll
    for (int off = 32; off; off >>= 1) lsv += __shfl_xor(lsv, off);
    float L = (float)(lsv + ls2);

    // q0 from t=0 row
    float x0 = (lane < KK) ? y_pred[(size_t)b * TT * KK + lane] : 0.0f;
    bool ok0 = (lane >= KK) || (x0 > -1e6f);
    bool m0 = (__ballot(ok0) == ~0ull);
    float xeff = (lane < KK) ? (m0 ? x0 : 0.0f) : 0.0f;
    float c0 = rdlanef(xeff, 0);
    float q0 = (lane < KK) ? fexp(xeff - c0) : 0.0f;

    float p = 0.0f;
    if (lane < KK) {
        for (int c = 0; c < KK; c++) {
            float qc = rdlanef(q0, c);
            p = fmaf(bf2f(Ub[c * PST + lane]), qc, p);
        }
    }
#pragma unroll
    for (int off = 32; off; off >>= 1) p += __shfl_xor(p, off);

    if (lane == 0) {
        out[b] = c0 + 0.6931471805599453f * (L + flog2(p)) - ws_target[b];
    }
}

extern "C" void kernel_launch(void* const* d_in, const int* in_sizes, int n_in,
                              void* d_out, int out_size, void* d_ws, size_t ws_size,
                              hipStream_t stream) {
    const float* y_true = (const float*)d_in[0];
    const float* y_pred = (const float*)d_in[1];
    const float* trans = (const float*)d_in[2];
    float* out = (float*)d_out;

    // adaptive segment count (r3 lesson: never overrun d_ws)
    int nseg = 16;
    if (ws_size >= (size_t)WS_U_OFF + (size_t)BB * 64 * SEGBYTES) nseg = 64;
    else if (ws_size >= (size_t)WS_U_OFF + (size_t)BB * 32 * SEGBYTES) nseg = 32;
    const int group = nseg / 16;

    float* ws_target = (float*)d_ws;
    int* ws_ls = (int*)((char*)d_ws + WS_LS_OFF);
    bf16_t* ws_u = (bf16_t*)((char*)d_ws + WS_U_OFF);

    hipMemsetAsync(ws_target, 0, BB * sizeof(float), stream);
    fused_kernel<<<dim3(nseg, BB), 256, 0, stream>>>(
        y_true, y_pred, trans, ws_target, ws_ls, ws_u, nseg);
    phaseA_kernel<<<dim3(16, BB), 64, 0, stream>>>(group, ws_u, ws_ls, nseg);
    phaseB_kernel<<<BB, 64, 0, stream>>>(y_pred, ws_u, ws_ls, ws_target, out, group, nseg);
}

// Round 8
// 299.176 us; speedup vs baseline: 1.1463x; 1.0411x over previous
//
#include <hip/hip_runtime.h>

#define BB 64
#define TT 4096
#define KK 48
#define UST 56              // stage1 Ubuf col stride (bf16): 112 B
#define PST 56              // phase LDS col stride (bf16)
#define WS_LS_OFF 256
#define WS_U_OFF 32768
#define SEGBYTES 6144       // 48 rows x 64 col-stride x bf16

typedef __bf16 bf16_t;
typedef bf16_t bf16x8 __attribute__((ext_vector_type(8)));
typedef float f32x4 __attribute__((ext_vector_type(4)));
typedef float f32x16 __attribute__((ext_vector_type(16)));

__device__ __forceinline__ float fexp(float x) {   // natural exp
    return __builtin_amdgcn_exp2f(x * 1.4426950408889634f);
}
__device__ __forceinline__ float flog2(float x) { return __builtin_amdgcn_logf(x); }
__device__ __forceinline__ float rdlanef(float v, int l) {
    return __int_as_float(__builtin_amdgcn_readlane(__float_as_int(v), l));
}
__device__ __forceinline__ unsigned int bf16bits(float f) {
    return (unsigned int)__builtin_bit_cast(unsigned short, (bf16_t)f);
}
__device__ __forceinline__ float bf2f(bf16_t h) {
    return __uint_as_float(((unsigned int)__builtin_bit_cast(unsigned short, h)) << 16);
}
__device__ __forceinline__ float ubf_lo(unsigned int w) { return __uint_as_float(w << 16); }
__device__ __forceinline__ float ubf_hi(unsigned int w) { return __uint_as_float(w & 0xffff0000u); }

// ============ fused: stage1 (waves 0-2) + ex-staging & scores (wave 3) ============
__global__ __launch_bounds__(256, 6) void fused_kernel(
    const float* __restrict__ y_true, const float* __restrict__ y_pred,
    const float* __restrict__ trans, float* __restrict__ ws_target,
    int* __restrict__ ws_ls, bf16_t* __restrict__ ws_u, int nseg) {
    const int s = blockIdx.x, b = blockIdx.y;
    const int seglen = TT / nseg;
    const int nch = seglen / 64;
    const int tid = threadIdx.x;
    const int w = tid >> 6;
    const int lane = tid & 63;
    const int q = lane >> 4;
    const int n = lane & 15;
    const int ncol = 16 * w + n;

    __shared__ __align__(16) uint2 exb[64 * 13];              // bf16x4 ex granules
    __shared__ __align__(16) bf16_t Ubuf[48 * UST + 16];
    __shared__ unsigned long long pb;
    __shared__ int lsb[4];

    // A fragments (waves 0-2): E^T zero-padded in K. A[m][k]: m=16mt+n, k=32ks+8q+j.
    bf16x8 afrag[3][2];
    if (w < 3) {
#pragma unroll
        for (int mt = 0; mt < 3; mt++) {
#pragma unroll
            for (int ks = 0; ks < 2; ks++) {
                bf16x8 f;
#pragma unroll
                for (int j = 0; j < 8; j++) {
                    int k = 32 * ks + 8 * q + j;
                    float v = (k < KK) ? fexp(trans[k * KK + 16 * mt + n]) : 0.0f;
                    f[j] = (bf16_t)v;
                }
                afrag[mt][ks] = f;
            }
        }
    }

    {   // zero Ubuf then identity diag
        uint4* p = (uint4*)Ubuf;
        for (int i = tid; i < (48 * UST + 16) / 8; i += 256) p[i] = make_uint4(0, 0, 0, 0);
    }
    __syncthreads();
    if (tid < KK) Ubuf[tid * UST + tid] = (bf16_t)1.0f;

    const bf16_t* bptr0 = &Ubuf[ncol * UST + 8 * q];
    const bf16_t* bptr1 = &Ubuf[ncol * UST + 32 + 8 * q];
    bf16_t* wp0 = &Ubuf[ncol * UST + 0 + 4 * q];
    bf16_t* wp1 = &Ubuf[ncol * UST + 16 + 4 * q];
    bf16_t* wp2 = &Ubuf[ncol * UST + 32 + 4 * q];

    f32x4 z4 = {0.0f, 0.0f, 0.0f, 0.0f};
    int ls = 0;
    float sc_acc = 0.0f;   // wave3: scores accumulator

    for (int ch = 0; ch < nch; ch++) {
        __syncthreads();                     // previous exb fully consumed
        if (w == 3) {
            // ---- producer + scores: lane = local timestep (b offset FIXED) ----
            const int t0c = s * seglen + ch * 64;
            const size_t rowbase = ((size_t)b * TT + t0c + lane) * KK;
            const float4* yp4 = (const float4*)(y_pred + rowbase);
            const float4* yt4 = (const float4*)(y_true + rowbase);
            float dot = 0.0f, labf = 0.0f, pmin = 1e30f;
            uint2* exrow = &exb[lane * 13];
#pragma unroll 4
            for (int g = 0; g < 12; g++) {
                float4 p = yp4[g];
                float4 a = yt4[g];
                dot = fmaf(a.x, p.x, fmaf(a.y, p.y, fmaf(a.z, p.z, fmaf(a.w, p.w, dot))));
                float e0 = (float)(4 * g);
                labf = fmaf(a.x, e0, fmaf(a.y, e0 + 1.0f, fmaf(a.z, e0 + 2.0f, fmaf(a.w, e0 + 3.0f, labf))));
                pmin = fminf(pmin, fminf(fminf(p.x, p.y), fminf(p.z, p.w)));
                exrow[g] = make_uint2(bf16bits(fexp(p.x)) | (bf16bits(fexp(p.y)) << 16),
                                      bf16bits(fexp(p.z)) | (bf16bits(fexp(p.w)) << 16));
            }
            bool mt_ok = pmin > -1e6f;
            unsigned long long bal = __ballot(mt_ok);
            if (lane == 0) pb = bal;

            // boundary row t0c+64 (label+mask), lanes 0..11 partials
            float labB = 0.0f, pmB = 1e30f;
            const bool hasB = (t0c + 64 < TT);
            if (hasB && lane < 12) {
                const size_t bdbase = ((size_t)b * TT + t0c + 64) * KK;
                float4 a = ((const float4*)(y_true + bdbase))[lane];
                float4 p = ((const float4*)(y_pred + bdbase))[lane];
                float e0 = (float)(4 * lane);
                labB = fmaf(a.x, e0, fmaf(a.y, e0 + 1.0f, fmaf(a.z, e0 + 2.0f, a.w * (e0 + 3.0f))));
                pmB = fminf(fminf(p.x, p.y), fminf(p.z, p.w));
            }
#pragma unroll
            for (int off = 1; off < 16; off <<= 1) {
                labB += __shfl_xor(labB, off);
                pmB = fminf(pmB, __shfl_xor(pmB, off));
            }
            int labB_i = (int)(rdlanef(labB, 0) + 0.5f);
            float mB = (hasB && rdlanef(pmB, 0) > -1e6f) ? 1.0f : 0.0f;

            int labt = (int)(labf + 0.5f);
            float mft = mt_ok ? 1.0f : 0.0f;
            int lnx = __shfl(labt, (lane + 1) & 63);
            float mnx = __shfl(mft, (lane + 1) & 63);
            if (lane == 63) { lnx = labB_i; mnx = mB; }
            sc_acc += mft * dot + mft * mnx * trans[labt * KK + lnx];
        }
        __syncthreads();
        if (w < 3) {
            const unsigned long long mk = pb;
            const int tt0 = (s == 0 && ch == 0) ? 1 : 0;
            for (int tt = tt0; tt < 64; tt++) {
                if (!((mk >> tt) & 1ull)) continue;

                bf16x8 bf0 = __builtin_bit_cast(bf16x8, *(const uint4*)bptr0);
                bf16x8 bf1 = __builtin_bit_cast(bf16x8, *(const uint4*)bptr1);

                f32x4 acc0 = __builtin_amdgcn_mfma_f32_16x16x32_bf16(afrag[0][0], bf0, z4, 0, 0, 0);
                acc0 = __builtin_amdgcn_mfma_f32_16x16x32_bf16(afrag[0][1], bf1, acc0, 0, 0, 0);
                f32x4 acc1 = __builtin_amdgcn_mfma_f32_16x16x32_bf16(afrag[1][0], bf0, z4, 0, 0, 0);
                acc1 = __builtin_amdgcn_mfma_f32_16x16x32_bf16(afrag[1][1], bf1, acc1, 0, 0, 0);
                f32x4 acc2 = __builtin_amdgcn_mfma_f32_16x16x32_bf16(afrag[2][0], bf0, z4, 0, 0, 0);
                acc2 = __builtin_amdgcn_mfma_f32_16x16x32_bf16(afrag[2][1], bf1, acc2, 0, 0, 0);

                uint2 w0 = exb[tt * 13 + q];          // ex rows 4q..4q+3
                uint2 w1 = exb[tt * 13 + 4 + q];      // ex rows 16+4q..
                uint2 w2 = exb[tt * 13 + 8 + q];      // ex rows 32+4q..
                float e00 = ubf_lo(w0.x), e01 = ubf_hi(w0.x), e02 = ubf_lo(w0.y), e03 = ubf_hi(w0.y);
                float e10 = ubf_lo(w1.x), e11 = ubf_hi(w1.x), e12 = ubf_lo(w1.y), e13 = ubf_hi(w1.y);
                float e20 = ubf_lo(w2.x), e21 = ubf_hi(w2.x), e22 = ubf_lo(w2.y), e23 = ubf_hi(w2.y);

                float v00 = rdlanef(acc0[0], 0);
                float sc = v00 * rdlanef(e00, 0);     // > 0
                int k = (int)(__float_as_uint(sc) >> 23) - 127;
                float r = __uint_as_float((unsigned int)(127 - k) << 23);   // 2^-k exact
                ls += k;

                {
                    float o0 = acc0[0] * (e00 * r), o1 = acc0[1] * (e01 * r);
                    float o2 = acc0[2] * (e02 * r), o3 = acc0[3] * (e03 * r);
                    *(uint2*)wp0 = make_uint2(bf16bits(o0) | (bf16bits(o1) << 16),
                                              bf16bits(o2) | (bf16bits(o3) << 16));
                }
                {
                    float o0 = acc1[0] * (e10 * r), o1 = acc1[1] * (e11 * r);
                    float o2 = acc1[2] * (e12 * r), o3 = acc1[3] * (e13 * r);
                    *(uint2*)wp1 = make_uint2(bf16bits(o0) | (bf16bits(o1) << 16),
                                              bf16bits(o2) | (bf16bits(o3) << 16));
                }
                {
                    float o0 = acc2[0] * (e20 * r), o1 = acc2[1] * (e21 * r);
                    float o2 = acc2[2] * (e22 * r), o3 = acc2[3] * (e23 * r);
                    *(uint2*)wp2 = make_uint2(bf16bits(o0) | (bf16bits(o1) << 16),
                                              bf16bits(o2) | (bf16bits(o3) << 16));
                }
            }
        }
    }

    // wave3: one atomic per block with the scores contribution
    if (w == 3) {
#pragma unroll
        for (int off = 32; off; off >>= 1) sc_acc += __shfl_xor(sc_acc, off);
        if (lane == 0) atomicAdd(&ws_target[b], sc_acc);
    }

    // reconcile per-wave pow2 scales (exact), write compact 48x64 bf16 block
    if (w < 3 && lane == 0) lsb[w] = ls;
    __syncthreads();
    if (w < 3 && lane < KK) {
        const int dl = ls - lsb[0];
        bf16_t* Uo = ws_u + (size_t)(b * nseg + s) * 3072;
        unsigned int wd[8];
#pragma unroll
        for (int j = 0; j < 8; j++) {
            float f0 = ldexpf(bf2f(Ubuf[(16 * w + 2 * j) * UST + lane]), dl);
            float f1 = ldexpf(bf2f(Ubuf[(16 * w + 2 * j + 1) * UST + lane]), dl);
            wd[j] = bf16bits(f0) | (bf16bits(f1) << 16);
        }
        *(uint4*)(Uo + (size_t)lane * 64 + 16 * w) = make_uint4(wd[0], wd[1], wd[2], wd[3]);
        *(uint4*)(Uo + (size_t)lane * 64 + 16 * w + 8) = make_uint4(wd[4], wd[5], wd[6], wd[7]);
    }
    if (tid == 0) ws_ls[b * nseg + s] = lsb[0];
}

// 48x48 product: D = A (global row-major 48x64) x W (LDS col-major stride PST), in place.
// Returns pow2 scale exponent removed. No barriers inside (single-wave safe).
__device__ __forceinline__ int chain_product(const bf16_t* __restrict__ A, bf16_t* Ub, int lane) {
    const int half = lane >> 5;
    const int l31 = lane & 31;
    f32x16 z16;
#pragma unroll
    for (int r = 0; r < 16; r++) z16[r] = 0.0f;

    bf16x8 af[2][3];
#pragma unroll
    for (int mt = 0; mt < 2; mt++) {
        int m = l31 + 32 * mt;
#pragma unroll
        for (int ks = 0; ks < 3; ks++) {
            if (m < KK)
                af[mt][ks] = __builtin_bit_cast(bf16x8, *(const uint4*)&A[(size_t)m * 64 + 16 * ks + 8 * half]);
            else
                af[mt][ks] = __builtin_bit_cast(bf16x8, make_uint4(0, 0, 0, 0));
        }
    }
    bf16x8 bg[3][2];
#pragma unroll
    for (int ks = 0; ks < 3; ks++)
#pragma unroll
        for (int nt = 0; nt < 2; nt++)
            bg[ks][nt] = __builtin_bit_cast(bf16x8, *(const uint4*)&Ub[(l31 + 32 * nt) * PST + 16 * ks + 8 * half]);

    f32x16 acc[4];
#pragma unroll
    for (int mt = 0; mt < 2; mt++)
#pragma unroll
        for (int nt = 0; nt < 2; nt++) {
            f32x16 a0 = __builtin_amdgcn_mfma_f32_32x32x16_bf16(af[mt][0], bg[0][nt], z16, 0, 0, 0);
            a0 = __builtin_amdgcn_mfma_f32_32x32x16_bf16(af[mt][1], bg[1][nt], a0, 0, 0, 0);
            acc[mt * 2 + nt] = __builtin_amdgcn_mfma_f32_32x32x16_bf16(af[mt][2], bg[2][nt], a0, 0, 0, 0);
        }

    float v00 = rdlanef(acc[0][0], 0);
    int k = (int)(__float_as_uint(v00) >> 23) - 127;
    float r = __uint_as_float((unsigned int)(127 - k) << 23);

#pragma unroll
    for (int mt = 0; mt < 2; mt++)
#pragma unroll
        for (int nt = 0; nt < 2; nt++) {
            int c = l31 + 32 * nt;
#pragma unroll
            for (int g = 0; g < 4; g++) {
                int a0 = 32 * mt + 8 * g + 4 * half;
                if (a0 < KK) {
                    const f32x16& Aq = acc[mt * 2 + nt];
                    unsigned int u0 = bf16bits(Aq[4 * g + 0] * r) | (bf16bits(Aq[4 * g + 1] * r) << 16);
                    unsigned int u1 = bf16bits(Aq[4 * g + 2] * r) | (bf16bits(Aq[4 * g + 3] * r) << 16);
                    *(uint2*)&Ub[c * PST + a0] = make_uint2(u0, u1);
                }
            }
        }
    return k;
}

// Variant: A read from LDS col-major slot (A[m][k] = As[k*PST + m]).
__device__ __forceinline__ int chain_product_ldsA(const bf16_t* As, bf16_t* Ub, int lane) {
    const int half = lane >> 5;
    const int l31 = lane & 31;
    f32x16 z16;
#pragma unroll
    for (int r = 0; r < 16; r++) z16[r] = 0.0f;

    bf16x8 af[2][3];
#pragma unroll
    for (int mt = 0; mt < 2; mt++) {
        int m = l31 + 32 * mt;
#pragma unroll
        for (int ks = 0; ks < 3; ks++) {
            bf16x8 f;
#pragma unroll
            for (int j = 0; j < 8; j++) {
                int k = 16 * ks + 8 * half + j;
                f[j] = (m < KK) ? As[k * PST + m] : (bf16_t)0.0f;
            }
            af[mt][ks] = f;
        }
    }
    bf16x8 bg[3][2];
#pragma unroll
    for (int ks = 0; ks < 3; ks++)
#pragma unroll
        for (int nt = 0; nt < 2; nt++)
            bg[ks][nt] = __builtin_bit_cast(bf16x8, *(const uint4*)&Ub[(l31 + 32 * nt) * PST + 16 * ks + 8 * half]);

    f32x16 acc[4];
#pragma unroll
    for (int mt = 0; mt < 2; mt++)
#pragma unroll
        for (int nt = 0; nt < 2; nt++) {
            f32x16 a0 = __builtin_amdgcn_mfma_f32_32x32x16_bf16(af[mt][0], bg[0][nt], z16, 0, 0, 0);
            a0 = __builtin_amdgcn_mfma_f32_32x32x16_bf16(af[mt][1], bg[1][nt], a0, 0, 0, 0);
            acc[mt * 2 + nt] = __builtin_amdgcn_mfma_f32_32x32x16_bf16(af[mt][2], bg[2][nt], a0, 0, 0, 0);
        }

    float v00 = rdlanef(acc[0][0], 0);
    int k = (int)(__float_as_uint(v00) >> 23) - 127;
    float r = __uint_as_float((unsigned int)(127 - k) << 23);

#pragma unroll
    for (int mt = 0; mt < 2; mt++)
#pragma unroll
        for (int nt = 0; nt < 2; nt++) {
            int c = l31 + 32 * nt;
#pragma unroll
            for (int g = 0; g < 4; g++) {
                int a0 = 32 * mt + 8 * g + 4 * half;
                if (a0 < KK) {
                    const f32x16& Aq = acc[mt * 2 + nt];
                    unsigned int u0 = bf16bits(Aq[4 * g + 0] * r) | (bf16bits(Aq[4 * g + 1] * r) << 16);
                    unsigned int u1 = bf16bits(Aq[4 * g + 2] * r) | (bf16bits(Aq[4 * g + 3] * r) << 16);
                    *(uint2*)&Ub[c * PST + a0] = make_uint2(u0, u1);
                }
            }
        }
    return k;
}

// ============ phase A: fold GROUP consecutive segment matrices, in place ============
__global__ __launch_bounds__(64) void phaseA_kernel(
    const int group, bf16_t* __restrict__ ws_u, int* __restrict__ ws_ls, int nseg) {
    const int g = blockIdx.x, b = blockIdx.y;
    const int lane = threadIdx.x;
    __shared__ __align__(16) bf16_t Ub[64 * PST];

    bf16_t* slot0 = ws_u + (size_t)(b * nseg + group * g) * 3072;
    for (int k = 0; k < KK; k++)
        Ub[lane * PST + k] = (lane < KK) ? slot0[(size_t)k * 64 + lane] : (bf16_t)0.0f;

    int lsk = ws_ls[b * nseg + group * g];
    __syncthreads();

    for (int j = 1; j < group; j++) {
        const bf16_t* A = ws_u + (size_t)(b * nseg + group * g + j) * 3072;
        lsk += ws_ls[b * nseg + group * g + j];
        lsk += chain_product(A, Ub, lane);
        __syncthreads();
    }

    for (int k = 0; k < KK; k++)
        slot0[(size_t)k * 64 + lane] = Ub[lane * PST + k];
    if (lane == 0) ws_ls[b * nseg + group * g] = lsk;
}

// ============ phase B: 4-wave tree over the 16 supersegments, apply q0, logsumexp ============
__global__ __launch_bounds__(256) void phaseB_kernel(
    const float* __restrict__ y_pred, const bf16_t* __restrict__ ws_u,
    const int* __restrict__ ws_ls, const float* __restrict__ ws_target,
    float* __restrict__ out, int group, int nseg) {
    const int b = blockIdx.x;
    const int tid = threadIdx.x;
    const int w = tid >> 6;
    const int lane = tid & 63;

    __shared__ __align__(16) bf16_t Ws[4][64 * PST];   // 4 x 7 KB
    __shared__ int lsw[4];

    // wave w: load supersegment 4w, fold 4w+1..4w+3 (depth 3, parallel across waves)
    const bf16_t* s0 = ws_u + (size_t)(b * nseg + group * (4 * w)) * 3072;
    for (int k = 0; k < KK; k++)
        Ws[w][lane * PST + k] = (lane < KK) ? s0[(size_t)k * 64 + lane] : (bf16_t)0.0f;
    int lsk = ws_ls[b * nseg + group * (4 * w)];
#pragma unroll
    for (int j = 1; j < 4; j++) {
        const bf16_t* A = ws_u + (size_t)(b * nseg + group * (4 * w + j)) * 3072;
        lsk += ws_ls[b * nseg + group * (4 * w + j)];
        lsk += chain_product(A, Ws[w], lane);
    }
    if (lane == 0) lsw[w] = lsk;
    __syncthreads();

    if (w == 0) {
        int ls2 = 0;
#pragma unroll
        for (int j = 1; j < 4; j++) ls2 += chain_product_ldsA(Ws[j], Ws[0], lane);

        float L = (float)(lsw[0] + lsw[1] + lsw[2] + lsw[3] + ls2);

        // q0 from t=0 row
        float x0 = (lane < KK) ? y_pred[(size_t)b * TT * KK + lane] : 0.0f;
        bool ok0 = (lane >= KK) || (x0 > -1e6f);
        bool m0 = (__ballot(ok0) == ~0ull);
        float xeff = (lane < KK) ? (m0 ? x0 : 0.0f) : 0.0f;
        float c0 = rdlanef(xeff, 0);
        float q0 = (lane < KK) ? fexp(xeff - c0) : 0.0f;

        float p = 0.0f;
        if (lane < KK) {
            for (int c = 0; c < KK; c++) {
                float qc = rdlanef(q0, c);
                p = fmaf(bf2f(Ws[0][c * PST + lane]), qc, p);
            }
        }
#pragma unroll
        for (int off = 32; off; off >>= 1) p += __shfl_xor(p, off);

        if (lane == 0) {
            out[b] = c0 + 0.6931471805599453f * (L + flog2(p)) - ws_target[b];
        }
    }
}

extern "C" void kernel_launch(void* const* d_in, const int* in_sizes, int n_in,
                              void* d_out, int out_size, void* d_ws, size_t ws_size,
                              hipStream_t stream) {
    const float* y_true = (const float*)d_in[0];
    const float* y_pred = (const float*)d_in[1];
    const float* trans = (const float*)d_in[2];
    float* out = (float*)d_out;

    // adaptive segment count (r3 lesson: never overrun d_ws)
    int nseg = 16;
    if (ws_size >= (size_t)WS_U_OFF + (size_t)BB * 64 * SEGBYTES) nseg = 64;
    else if (ws_size >= (size_t)WS_U_OFF + (size_t)BB * 32 * SEGBYTES) nseg = 32;
    const int group = nseg / 16;

    float* ws_target = (float*)d_ws;
    int* ws_ls = (int*)((char*)d_ws + WS_LS_OFF);
    bf16_t* ws_u = (bf16_t*)((char*)d_ws + WS_U_OFF);

    hipMemsetAsync(ws_target, 0, BB * sizeof(float), stream);
    fused_kernel<<<dim3(nseg, BB), 256, 0, stream>>>(
        y_true, y_pred, trans, ws_target, ws_ls, ws_u, nseg);
    phaseA_kernel<<<dim3(16, BB), 64, 0, stream>>>(group, ws_u, ws_ls, nseg);
    phaseB_kernel<<<BB, 256, 0, stream>>>(y_pred, ws_u, ws_ls, ws_target, out, group, nseg);
}